// Round 7
// baseline (761.845 us; speedup 1.0000x reference)
//
#include <hip/hip_runtime.h>

// Zero-phase bandpass FIR = one 8191-tap correlation with the kernel
// autocorrelation g:  out[j][t] = sum_s g[s] * xe[j][t+s]  (g bf16-hi, x bf16).
// Round 7: 32x32x16 MFMA formulation. C[m][j] tiles (m = time offset, j = all
// 32 signal rows). Toeplitz A_c[m][k] = g[16c + k - m]; B_W[k][j] =
// xe[j][16(vb+W)+k]. Tile mt at window W uses c = W - 2mt and the SAME B_W
// -> per W-step: 1 A-frag (16-deep register ring, reused by 8 tiles) +
// 1 B ds_read + 8 MFMAs. Per-CU: MFMA 512 cyc vs L1 256 vs LDS 128 / W-round.
// Block = 8 waves (4 c-quarters x 2 subgroups), private 8-slot LDS B-rings
// staged by global_load_lds, vmcnt(0) per 4-W superstep, no loop barriers.

#define T_LEN  131072
#define NW     8720          // xeT windows (16 t each)
#define WQ     136           // W-steps per c-quarter (4*136 = 544 covers all)
#define NSS    34            // supersteps of 4 W
#define NATAB  580           // A chunks, idx = c + 32

typedef float  f32x4  __attribute__((ext_vector_type(4)));
typedef float  f32x16 __attribute__((ext_vector_type(16)));
typedef __bf16 bf16x8 __attribute__((ext_vector_type(8)));

// ---------- ws layout (bytes) ----------
#define WS_G    0            // 8192 floats (autocorrelation)
#define WS_ATAB 32768        // 580*1024 B bf16 Toeplitz frags
#define WS_XET  626688       // 8720*1024 B window-major swizzled signal
#define WS_END  9555968

__device__ __forceinline__ void gload_lds16(const uint4* g, uint4* lds) {
  __builtin_amdgcn_global_load_lds(
      (const __attribute__((address_space(1))) unsigned int*)g,
      (__attribute__((address_space(3))) unsigned int*)lds, 16, 0, 0);
}

// K1: xeT build (+ zero g). Window v: logical slot u = 2j + q8 holds
// xe_row_j[16v + 8*q8 + 0..8) as bf16; stored at phys slot p = u^((u>>3)&7)
// so identity-lane staging + swizzled ds_read is bank-conflict-free.
__global__ void k_build_xeT(const float* __restrict__ x, uint4* __restrict__ xeT,
                            float* __restrict__ g) {
  int idx = blockIdx.x * 256 + threadIdx.x;
  if (idx < 2048) *(float4*)((float*)g + idx * 4) = make_float4(0.f, 0.f, 0.f, 0.f);
  if (idx >= NW * 64) return;
  int v = idx >> 6, pp = idx & 63;
  int u = pp ^ ((pp >> 3) & 7);
  int j = u >> 1, q8 = u & 1;
  const float* xr = x + (size_t)j * T_LEN;
  int w0 = (v << 4) + (q8 << 3);
  int v0 = w0 - 4095;                       // xe[w] = X(w-4095)
  bf16x8 o;
  if (v0 >= 0 && v0 <= T_LEN - 8) {
    float4 f0, f1;
    __builtin_memcpy(&f0, xr + v0, 16);
    __builtin_memcpy(&f1, xr + v0 + 4, 16);
    o[0] = (__bf16)f0.x; o[1] = (__bf16)f0.y; o[2] = (__bf16)f0.z; o[3] = (__bf16)f0.w;
    o[4] = (__bf16)f1.x; o[5] = (__bf16)f1.y; o[6] = (__bf16)f1.z; o[7] = (__bf16)f1.w;
  } else {
    #pragma unroll
    for (int e = 0; e < 8; ++e) {
      int vv = v0 + e;
      float val = 0.0f;
      if (vv >= -2048 && vv < T_LEN + 2048) {
        int v2 = vv < 0 ? -vv : vv;
        v2 = v2 >= T_LEN ? 2 * T_LEN - 2 - v2 : v2;
        val = xr[v2];
      }
      o[e] = (__bf16)val;
    }
  }
  xeT[(size_t)v * 64 + pp] = __builtin_bit_cast(uint4, o);
}

// K2: autocorr direct from k (predicated, no padded copy).
// g[s] = sum_{i=0}^{s} k[i]*k[i + 4095 - s], mirrored to g[8190-s].
__global__ void k_autocorr(const float* __restrict__ k, float* __restrict__ g) {
  int s = blockIdx.x * 256 + threadIdx.x;   // [0, 4096)
  int i0 = blockIdx.y * 256;
  int d = 4095 - s;
  float a0 = 0.f, a1 = 0.f, a2 = 0.f, a3 = 0.f;
  #pragma unroll 4
  for (int i = 0; i < 256; i += 4) {
    int b = i0 + i;
    if (b + 0 <= s) a0 = fmaf(k[b + 0], k[b + 0 + d], a0);
    if (b + 1 <= s) a1 = fmaf(k[b + 1], k[b + 1 + d], a1);
    if (b + 2 <= s) a2 = fmaf(k[b + 2], k[b + 2 + d], a2);
    if (b + 3 <= s) a3 = fmaf(k[b + 3], k[b + 3 + d], a3);
  }
  float part = (a0 + a1) + (a2 + a3);
  atomicAdd(&g[s], part);
  if (s != 4095) atomicAdd(&g[8190 - s], part);
}

// K3: A-table, fragment-ordered [cidx][lane][8 bf16], cidx = c + 32.
// Lane l: m = l&31, k = (l>>5)*8 + jj; val = g[16c + k - m] (0 outside).
__global__ void k_build_atab(const float* __restrict__ g, __bf16* __restrict__ A) {
  int cidx = blockIdx.x;
  int t = threadIdx.x;
  int l = t >> 2, jj0 = (t & 3) * 2;
  int m = l & 31, q8 = l >> 5;
  int c = cidx - 32;
  #pragma unroll
  for (int e = 0; e < 2; ++e) {
    int kk = (q8 << 3) + jj0 + e;
    int s = 16 * c + kk - m;
    float val = (s >= 0 && s <= 8190) ? g[s] : 0.0f;
    A[(size_t)cidx * 512 + l * 8 + jj0 + e] = (__bf16)val;
  }
}

// one 4-W superstep; P4 = (ss&3)*4 compile-time for register-ring indexing
template <int P4>
__device__ __forceinline__ void superstep(
    int ss, const uint4* __restrict__ bsrc, const uint4* __restrict__ asrc,
    uint4* __restrict__ ring, int p, uint4 (&Areg)[16], f32x16 (&acc)[8]) {
  asm volatile("s_waitcnt vmcnt(0)" ::: "memory");   // ring[this ss] ready
  if (ss + 1 < NSS) {                                 // async-stage next 4 slots
    const uint4* bs = bsrc + ((size_t)(ss + 1) << 8);
    uint4* rs = ring + (((P4 & 7) ^ 4) << 6);
    #pragma unroll
    for (int i = 0; i < 4; ++i)
      gload_lds16(bs + (i << 6), rs + (i << 6));
  }
  #pragma unroll
  for (int i = 0; i < 4; ++i) {
    const int Wl = (ss << 2) + i;
    bf16x8 B = __builtin_bit_cast(bf16x8, ring[(((P4 & 7) + i) << 6) + p]);
    #pragma unroll
    for (int mt = 0; mt < 8; ++mt) {
      bf16x8 A = __builtin_bit_cast(bf16x8, Areg[(P4 + i - 2 * mt) & 15]);
      acc[mt] = __builtin_amdgcn_mfma_f32_32x32x16_bf16(A, B, acc[mt], 0, 0, 0);
    }
    // refill ring slot just freed (A(Wl-14) dead after step Wl)
    Areg[(P4 + i + 2) & 15] = *(asrc + (ptrdiff_t)(Wl + 2) * 64);
  }
}

// Main: 512 thr = 8 waves: wave = (cq, sg), cq = c-quarter, sg = tile group.
// Wave tiles g = 8sg + mt (mt<8), t = t0b + 32g + m. c = W - 16sg - 2mt,
// W = cq*WQ + Wl. Grid 256 blocks (1/CU), 2 waves/SIMD, 64 KB LDS rings.
__global__ __launch_bounds__(512, 2) void k_fir_mfma(
    const uint4* __restrict__ xeT, const uint4* __restrict__ Atab,
    float* __restrict__ out) {
  __shared__ uint4 smem[4096];               // 8 waves x 8 slots x 1 KB

  const int tid = threadIdx.x;
  const int wv = tid >> 6, cq = wv >> 1, sg = wv & 1;
  const int l = tid & 63, j = l & 31, q8 = l >> 5;
  const int bx = blockIdx.x, t0b = bx << 9;
  const int u = (j << 1) | q8;
  const int p = u ^ ((u >> 3) & 7);          // swizzled B slot (conflict-free)

  const uint4* bsrc = xeT + ((size_t)((bx << 5) + cq * WQ) << 6) + l;
  const uint4* asrc = Atab + ((size_t)(cq * WQ - 16 * sg + 32) << 6) + l;
  uint4* ring = smem + (wv << 9);

  f32x16 acc[8];
  {
    f32x16 z;
    #pragma unroll
    for (int e = 0; e < 16; ++e) z[e] = 0.f;
    #pragma unroll
    for (int mt = 0; mt < 8; ++mt) acc[mt] = z;
  }

  uint4 Areg[16];
  // prologue: stage ss=0 slots, fill A ring for Wl in [-14, 2)
  #pragma unroll
  for (int i = 0; i < 4; ++i)
    gload_lds16(bsrc + (i << 6), ring + (i << 6));
  #pragma unroll
  for (int w2 = -14; w2 < 2; ++w2)
    Areg[w2 & 15] = *(asrc + (ptrdiff_t)w2 * 64);

  for (int ss = 0; ss < NSS; ++ss) {
    switch (ss & 3) {
      case 0: superstep<0>(ss, bsrc, asrc, ring, p, Areg, acc); break;
      case 1: superstep<4>(ss, bsrc, asrc, ring, p, Areg, acc); break;
      case 2: superstep<8>(ss, bsrc, asrc, ring, p, Areg, acc); break;
      default: superstep<12>(ss, bsrc, asrc, ring, p, Areg, acc); break;
    }
  }

  // ---- combine 4 c-quarters in LDS (2 rounds of 8 tiles), then store ----
  // C/D: col = j = lane&31, row m = (reg&3) + 8*(reg>>2) + 4*(lane>>5).
  float* Cf = (float*)smem;                  // 8 tiles x 32j x 36m floats
  const int co = j * 36 + (q8 << 2);
  #pragma unroll 1
  for (int half = 0; half < 2; ++half) {
    __syncthreads();                          // rings / previous copy dead
    #pragma unroll 1
    for (int ph = 0; ph < 4; ++ph) {
      if (cq == ph) {
        #pragma unroll
        for (int mi = 0; mi < 4; ++mi) {
          const int mt = half * 4 + mi;
          float* cp = Cf + ((sg << 2) + mi) * 1152 + co;
          #pragma unroll
          for (int rq = 0; rq < 4; ++rq) {
            f32x4 v;
            v[0] = acc[mt][4 * rq + 0]; v[1] = acc[mt][4 * rq + 1];
            v[2] = acc[mt][4 * rq + 2]; v[3] = acc[mt][4 * rq + 3];
            float* dst = cp + (rq << 3);
            if (ph != 0) v += *(const f32x4*)dst;
            *(f32x4*)dst = v;
          }
        }
      }
      __syncthreads();
    }
    {
      const int j2 = tid >> 4, s5 = (tid & 15) >> 1, mh = tid & 1;
      const int g5 = ((s5 >> 2) << 3) + half * 4 + (s5 & 3);
      const float* src = Cf + s5 * 1152 + j2 * 36 + (mh << 4);
      float* dst = out + (size_t)j2 * T_LEN + t0b + (g5 << 5) + (mh << 4);
      #pragma unroll
      for (int u2 = 0; u2 < 4; ++u2)
        *(f32x4*)(dst + (u2 << 2)) = *(const f32x4*)(src + (u2 << 2));
    }
  }
}

extern "C" void kernel_launch(void* const* d_in, const int* in_sizes, int n_in,
                              void* d_out, int out_size, void* d_ws, size_t ws_size,
                              hipStream_t stream) {
  const float* x = (const float*)d_in[0];
  const float* k = (const float*)d_in[1];
  float* out = (float*)d_out;
  char* ws = (char*)d_ws;
  if (ws_size < (size_t)WS_END) return;

  float*  g    = (float*)(ws + WS_G);
  __bf16* Atab = (__bf16*)(ws + WS_ATAB);
  uint4*  xeT  = (uint4*)(ws + WS_XET);

  k_build_xeT<<<dim3((NW * 64 + 255) / 256), dim3(256), 0, stream>>>(x, xeT, g);
  k_autocorr<<<dim3(16, 16), dim3(256), 0, stream>>>(k, g);
  k_build_atab<<<dim3(NATAB), dim3(256), 0, stream>>>(g, Atab);
  k_fir_mfma<<<dim3(256), dim3(512), 0, stream>>>(
      xeT, (const uint4*)Atab, out);
}